// Round 4
// baseline (969.220 us; speedup 1.0000x reference)
//
#include <hip/hip_runtime.h>
#include <hip/hip_bf16.h>

// FlowEmbedding (B=4, N=M=4096, C=64, S=32, mlp=[64,64,64]) — f32 I/O.
// R4: MFMA (16x16x32 bf16) for gram0/gram1/final; bf16 y-tiles in LDS with
//     XOR swizzle; BN scales folded into bf16 weight copies; stats in f32.

#define N_ 4096
#define S_ 32
#define PTOT 524288.0f   // B*N*S

typedef unsigned short u16;
typedef unsigned int   u32;
typedef __attribute__((ext_vector_type(8))) short short8;  // 8 bf16 (4 VGPR)
typedef __attribute__((ext_vector_type(4))) float f32x4;

__device__ __forceinline__ u16 f2b(float f){
  __hip_bfloat16 h = __float2bfloat16(f);
  return *(u16*)&h;
}
// swizzled u16 index into a [64][64] bf16 LDS tile (rows 128 B): bank-conflict-free
__device__ __forceinline__ int TIX(int r, int c){ return (r << 6) + (c ^ ((r & 7) << 3)); }
#define MFMA16(a,b,c) __builtin_amdgcn_mfma_f32_16x16x32_bf16((a),(b),(c),0,0,0)

// ---------------- copy pos1 (output 0 passthrough) ---------------------------
__global__ void k_copy(const uint4* __restrict__ s, uint4* __restrict__ d){
  int i = blockIdx.x * 256 + threadIdx.x;   // 48 x 256 = 12288 exact
  d[i] = s[i];
}

// ---------------- KNN: one query per wave, lane-distributed sorted top-32 ----
__global__ __launch_bounds__(256) void k_knn(const float* __restrict__ pos1,
        const float* __restrict__ pos2, int* __restrict__ idxb){
  int b = blockIdx.y;
  int lane = threadIdx.x & 63;
  int n = blockIdx.x * 4 + (threadIdx.x >> 6);
  const float* p1 = pos1 + b * 3 * N_;
  const float* p2 = pos2 + b * 3 * N_;
  float qx = p1[n], qy = p1[N_ + n], qz = p1[2 * N_ + n];
  float v = 3.4e38f; int vi = 0;
  float w32 = 3.4e38f;
  for (int c0 = 0; c0 < N_; c0 += 64){
    int j = c0 + lane;
    float dx = p2[j] - qx;
    float dy = p2[N_ + j] - qy;
    float dz = p2[2 * N_ + j] - qz;
    float dsq = dx * dx + dy * dy + dz * dz;
    unsigned long long mask = __ballot(dsq < w32);
    while (mask){
      int s = __builtin_ctzll(mask); mask &= mask - 1;
      float xd = __shfl(dsq, s);
      int   xj = c0 + s;
      int rank = __popcll(__ballot(v < xd));
      float pv = __shfl_up(v, 1);
      int   pi = __shfl_up(vi, 1);
      if (lane >= rank){
        if (lane == rank){ v = xd; vi = xj; }
        else             { v = pv; vi = pi; }
      }
      if (lane >= 32) v = 3.4e38f;
      w32 = __shfl(v, 31);
    }
  }
  int best = __shfl(vi, 0);
  if (lane < 32){
    int id = (v > 25.0f) ? best : vi;
    idxb[(b * N_ + n) * S_ + lane] = id;
  }
}

// ---------------- layer-0 factorization: A (MODE=0) / Cn (MODE=1) -----------
template<int MODE>
__global__ __launch_bounds__(256) void k_precomp(const float* __restrict__ posx,
        const float* __restrict__ featx, const float* __restrict__ W0,
        float* __restrict__ outp){
  __shared__ float Ws[67][65];
  __shared__ float Xs[67][65];
  int b = blockIdx.y, j0 = blockIdx.x * 64, t = threadIdx.x;
  for (int e = t; e < 67 * 64; e += 256){
    int r = e >> 6, o = e & 63;
    int wc = (MODE == 0) ? r : (r < 3 ? r : r + 64);
    Ws[r][o] = W0[o * 131 + wc];
    float x;
    if (r < 3){ x = posx[(b * 3 + r) * N_ + j0 + o]; if (MODE) x = -x; }
    else        x = featx[(b * 64 + (r - 3)) * N_ + j0 + o];
    Xs[r][o] = x;
  }
  __syncthreads();
  int og = t & 15, sl = t >> 4;
  float acc[4][4] = {};
  for (int r = 0; r < 67; ++r){
    float w0v = Ws[r][og*4+0], w1v = Ws[r][og*4+1], w2v = Ws[r][og*4+2], w3v = Ws[r][og*4+3];
    #pragma unroll
    for (int c = 0; c < 4; ++c){
      float xv = Xs[r][sl*4+c];
      acc[c][0] += xv*w0v; acc[c][1] += xv*w1v; acc[c][2] += xv*w2v; acc[c][3] += xv*w3v;
    }
  }
  #pragma unroll
  for (int c = 0; c < 4; ++c){
    float4 val; val.x = acc[c][0]; val.y = acc[c][1]; val.z = acc[c][2]; val.w = acc[c][3];
    *(float4*)&outp[((size_t)(b * N_ + j0 + sl*4 + c)) * 64 + og*4] = val;
  }
}

// ---------------- stats of h0 (pre-BN0): direct gather, float4 --------------
__global__ __launch_bounds__(256) void k_stats0(const int* __restrict__ idxb,
    const float* __restrict__ A, const float* __restrict__ Cn,
    float* __restrict__ sum0, float* __restrict__ sumsq0){
  int b = blockIdx.y, n0 = blockIdx.x * 32;
  int c4 = threadIdx.x & 15, sq = threadIdx.x >> 4;
  float4 a1 = {0,0,0,0}, a2 = {0,0,0,0};
  for (int q = 0; q < 32; ++q){
    int n = n0 + q;
    float4 cv = *(const float4*)&Cn[((size_t)(b * N_ + n)) * 64 + c4 * 4];
    const int* ip = idxb + (b * N_ + n) * 32;
    #pragma unroll
    for (int ss = 0; ss < 2; ++ss){
      int j = ip[sq + ss * 16];
      float4 av = *(const float4*)&A[((size_t)(b * N_ + j)) * 64 + c4 * 4];
      float h0 = av.x + cv.x, h1 = av.y + cv.y, h2 = av.z + cv.z, h3 = av.w + cv.w;
      a1.x += h0; a1.y += h1; a1.z += h2; a1.w += h3;
      a2.x += h0*h0; a2.y += h1*h1; a2.z += h2*h2; a2.w += h3*h3;
    }
  }
  __shared__ float red1[16][64];
  __shared__ float red2[16][64];
  *(float4*)&red1[sq][c4*4] = a1;
  *(float4*)&red2[sq][c4*4] = a2;
  __syncthreads();
  int t = threadIdx.x;
  if (t < 64){
    float s1 = 0.f, s2 = 0.f;
    #pragma unroll
    for (int k = 0; k < 16; ++k){ s1 += red1[k][t]; s2 += red2[k][t]; }
    atomicAdd(&sum0[t], s1);
    atomicAdd(&sumsq0[t], s2);
  }
}

// ---------------- BN param kernels ------------------------------------------
__global__ void k_bn0(const float* sum0, const float* sumsq0, const float* g,
                      const float* bb, float* bnp){
  int c = threadIdx.x;
  float m = sum0[c] * (1.0f / PTOT);
  float v = sumsq0[c] * (1.0f / PTOT) - m * m;
  v = v > 0.f ? v : 0.f;
  float sc = g[c] * rsqrtf(v + 1e-5f);
  bnp[c] = sc; bnp[64 + c] = bb[c] - m * sc;
}

// stats of h=W*y from Gram; emits bf16 weight copy Wb[o][c] = sc[o]*W[o][c]
__global__ void k_bnW(const float* __restrict__ W, const float* __restrict__ r,
    const float* __restrict__ G, const float* g, const float* bb, float* bnp,
    u16* __restrict__ Wb){
  int o = threadIdx.x;
  float mean = 0.f;
  for (int c = 0; c < 64; ++c) mean += W[o * 64 + c] * r[c];
  float qq = 0.f;
  for (int c = 0; c < 64; ++c){
    float wc = W[o * 64 + c];
    float t1 = 0.f;
    for (int d = 0; d < 64; ++d) t1 += G[c * 64 + d] * W[o * 64 + d];
    qq += wc * t1;
  }
  float m = mean * (1.0f / PTOT);
  float v = qq * (1.0f / PTOT) - m * m;
  v = v > 0.f ? v : 0.f;
  float sc = g[o] * rsqrtf(v + 1e-5f);
  bnp[o] = sc; bnp[64 + o] = bb[o] - m * sc;
  for (int c = 0; c < 64; ++c) Wb[o * 64 + c] = f2b(sc * W[o * 64 + c]);
}

// ---------------- fold BN0 into A (MODE=0) / Cn (MODE=1), in place ----------
template<int MODE>
__global__ void k_scaleAC(float* __restrict__ X, const float* __restrict__ bnp){
  int i = blockIdx.x * 256 + threadIdx.x;   // float4 index; 1024 x 256
  float4 v = ((float4*)X)[i];
  int c4 = i & 15;
  float4 sc = *(const float4*)&bnp[c4 * 4];
  if (MODE == 0){
    v.x *= sc.x; v.y *= sc.y; v.z *= sc.z; v.w *= sc.w;
  } else {
    float4 sh = *(const float4*)&bnp[64 + c4 * 4];
    v.x = v.x * sc.x + sh.x; v.y = v.y * sc.y + sh.y;
    v.z = v.z * sc.z + sh.z; v.w = v.w * sc.w + sh.w;
  }
  ((float4*)X)[i] = v;
}

// gather one 64-point chunk, compute y0 = relu(A'+Cn') (f32), return 16 ch vals
#define GATHER_Y0(YARR)                                                       \
  int nq = n0 + ch * 2 + (l >> 5);                                            \
  int jj = idxb[((b << 12) + nq) * 32 + (l & 31)];                            \
  const float* ap = A + (((size_t)((b << 12) + jj)) << 6) + (w << 4);         \
  const float* cp = Cn + (((size_t)((b << 12) + nq)) << 6) + (w << 4);        \
  float YARR[16];                                                             \
  _Pragma("unroll")                                                           \
  for (int k = 0; k < 16; k += 4){                                            \
    float4 av = *(const float4*)(ap + k);                                     \
    float4 cv = *(const float4*)(cp + k);                                     \
    YARR[k+0] = fmaxf(av.x + cv.x, 0.f);                                      \
    YARR[k+1] = fmaxf(av.y + cv.y, 0.f);                                      \
    YARR[k+2] = fmaxf(av.z + cv.z, 0.f);                                      \
    YARR[k+3] = fmaxf(av.w + cv.w, 0.f);                                      \
  }

// ---------------- gram0: G0 = sum y0 y0^T, r0 = sum y0 (MFMA) ---------------
__global__ __launch_bounds__(256) void k_gram0(const int* __restrict__ idxb,
    const float* __restrict__ A, const float* __restrict__ Cn,
    float* __restrict__ G0, float* __restrict__ r0){
  __shared__ u16 yc[4096];                   // y0 [c][p] bf16, swizzled
  int b = blockIdx.y, n0 = blockIdx.x * 16, t = threadIdx.x;
  int l = t & 63, w = t >> 6;
  f32x4 acc[4] = {};
  float rsum[16] = {};
  for (int ch = 0; ch < 8; ++ch){
    GATHER_Y0(yv)                            // lane: p = l, channels w*16..+15
    #pragma unroll
    for (int k = 0; k < 16; ++k){
      rsum[k] += yv[k];
      yc[TIX((w << 4) + k, l)] = f2b(yv[k]);
    }
    __syncthreads();
    #pragma unroll
    for (int ks = 0; ks < 2; ++ks){
      short8 bf = *(const short8*)&yc[TIX((w << 4) + (l & 15), ks * 32 + ((l >> 4) << 3))];
      #pragma unroll
      for (int ta = 0; ta < 4; ++ta){
        short8 af = *(const short8*)&yc[TIX(ta * 16 + (l & 15), ks * 32 + ((l >> 4) << 3))];
        acc[ta] = MFMA16(af, bf, acc[ta]);
      }
    }
    __syncthreads();                         // before next chunk overwrites yc
  }
  #pragma unroll
  for (int ta = 0; ta < 4; ++ta)
    #pragma unroll
    for (int r = 0; r < 4; ++r)
      atomicAdd(&G0[(ta*16 + ((l>>4)<<2) + r) * 64 + (w<<4) + (l & 15)], acc[ta][r]);
  #pragma unroll
  for (int i = 0; i < 16; ++i){
    float v = rsum[i];
    #pragma unroll
    for (int s = 32; s >= 1; s >>= 1) v += __shfl_xor(v, s);
    if (l == 0) atomicAdd(&r0[(w<<4) + i], v);
  }
}

// ---------------- gram1: y1 = relu(W1b*y0 + sh1); G1, r1 (MFMA) -------------
__global__ __launch_bounds__(256) void k_gram1(const int* __restrict__ idxb,
    const float* __restrict__ A, const float* __restrict__ Cn,
    const u16* __restrict__ W1b, const float* __restrict__ bnp1,
    float* __restrict__ G1, float* __restrict__ r1o){
  __shared__ u16 yp[4096];                   // y0 [p][c] bf16, swizzled
  __shared__ u16 y1c[4096];                  // y1 [c][p] bf16, swizzled
  __shared__ float sh1[64];
  __shared__ float rsh[64];
  int b = blockIdx.y, n0 = blockIdx.x * 16, t = threadIdx.x;
  int l = t & 63, w = t >> 6;
  if (t < 64){ sh1[t] = bnp1[64 + t]; rsh[t] = 0.f; }
  short8 wf[4][2];
  #pragma unroll
  for (int to = 0; to < 4; ++to)
    #pragma unroll
    for (int ks = 0; ks < 2; ++ks)
      wf[to][ks] = *(const short8*)&W1b[(to*16 + (l & 15)) * 64 + ks*32 + ((l>>4)<<3)];
  __syncthreads();
  float sh1v[4][4];
  #pragma unroll
  for (int to = 0; to < 4; ++to)
    #pragma unroll
    for (int r = 0; r < 4; ++r)
      sh1v[to][r] = sh1[to*16 + ((l>>4)<<2) + r];
  f32x4 gacc[4] = {};
  float rs[4][4] = {};
  for (int ch = 0; ch < 8; ++ch){
    GATHER_Y0(yv)                            // lane: p = l, channels w*16..+15
    short8 s0, s1;
    #pragma unroll
    for (int i = 0; i < 8; ++i){ s0[i] = (short)f2b(yv[i]); s1[i] = (short)f2b(yv[8+i]); }
    *(short8*)&yp[TIX(l, (w<<4))] = s0;
    *(short8*)&yp[TIX(l, (w<<4) + 8)] = s1;
    __syncthreads();
    // layer1: D[o][p] = sum_c W1b[o][c] * y0[c][p]; wave w owns p-tile w
    short8 bf0 = *(const short8*)&yp[TIX((w<<4) + (l & 15), ((l>>4)<<3))];
    short8 bf1 = *(const short8*)&yp[TIX((w<<4) + (l & 15), 32 + ((l>>4)<<3))];
    f32x4 h[4] = {};
    #pragma unroll
    for (int to = 0; to < 4; ++to){
      h[to] = MFMA16(wf[to][0], bf0, h[to]);
      h[to] = MFMA16(wf[to][1], bf1, h[to]);
    }
    int pcol = (w<<4) + (l & 15);
    #pragma unroll
    for (int to = 0; to < 4; ++to)
      #pragma unroll
      for (int r = 0; r < 4; ++r){
        int o = to*16 + ((l>>4)<<2) + r;
        float y = h[to][r] + sh1v[to][r];
        y = y > 0.f ? y : 0.f;
        rs[to][r] += y;
        y1c[TIX(o, pcol)] = f2b(y);
      }
    __syncthreads();
    // gram over y1
    #pragma unroll
    for (int ks = 0; ks < 2; ++ks){
      short8 bf = *(const short8*)&y1c[TIX((w<<4) + (l & 15), ks*32 + ((l>>4)<<3))];
      #pragma unroll
      for (int ta = 0; ta < 4; ++ta){
        short8 af = *(const short8*)&y1c[TIX(ta*16 + (l & 15), ks*32 + ((l>>4)<<3))];
        gacc[ta] = MFMA16(af, bf, gacc[ta]);
      }
    }
  }
  #pragma unroll
  for (int ta = 0; ta < 4; ++ta)
    #pragma unroll
    for (int r = 0; r < 4; ++r)
      atomicAdd(&G1[(ta*16 + ((l>>4)<<2) + r) * 64 + (w<<4) + (l & 15)], gacc[ta][r]);
  #pragma unroll
  for (int to = 0; to < 4; ++to)
    #pragma unroll
    for (int r = 0; r < 4; ++r){
      float v = rs[to][r];
      #pragma unroll
      for (int s = 1; s <= 8; s <<= 1) v += __shfl_xor(v, s);
      if ((l & 15) == 0) atomicAdd(&rsh[to*16 + ((l>>4)<<2) + r], v);
    }
  __syncthreads();
  if (t < 64) atomicAdd(&r1o[t], rsh[t]);
}

// ---------------- final: layer1 + layer2 + maxpool -> out (MFMA) ------------
__global__ __launch_bounds__(256) void k_final(const int* __restrict__ idxb,
    const float* __restrict__ A, const float* __restrict__ Cn,
    const u16* __restrict__ W1b, const u16* __restrict__ W2b,
    const float* __restrict__ bnp1, const float* __restrict__ bnp2,
    float* __restrict__ outp){
  __shared__ u16 yp[4096];                   // y0 [p][c]
  __shared__ u16 y1p[4096];                  // y1 [p][c]
  __shared__ float sh1[64], sh2[64];
  __shared__ u32 omax[1024];                 // [q][o]
  int b = blockIdx.y, n0 = blockIdx.x * 16, t = threadIdx.x;
  int l = t & 63, w = t >> 6;
  if (t < 64){ sh1[t] = bnp1[64 + t]; sh2[t] = bnp2[64 + t]; }
  for (int e = t; e < 1024; e += 256) omax[e] = 0u;
  short8 wf1[4][2], wf2[4][2];
  #pragma unroll
  for (int to = 0; to < 4; ++to)
    #pragma unroll
    for (int ks = 0; ks < 2; ++ks){
      wf1[to][ks] = *(const short8*)&W1b[(to*16 + (l & 15)) * 64 + ks*32 + ((l>>4)<<3)];
      wf2[to][ks] = *(const short8*)&W2b[(to*16 + (l & 15)) * 64 + ks*32 + ((l>>4)<<3)];
    }
  __syncthreads();
  float sh1v[4][4], sh2v[4][4];
  #pragma unroll
  for (int to = 0; to < 4; ++to)
    #pragma unroll
    for (int r = 0; r < 4; ++r){
      sh1v[to][r] = sh1[to*16 + ((l>>4)<<2) + r];
      sh2v[to][r] = sh2[to*16 + ((l>>4)<<2) + r];
    }
  for (int ch = 0; ch < 8; ++ch){
    GATHER_Y0(yv)
    short8 s0, s1;
    #pragma unroll
    for (int i = 0; i < 8; ++i){ s0[i] = (short)f2b(yv[i]); s1[i] = (short)f2b(yv[8+i]); }
    *(short8*)&yp[TIX(l, (w<<4))] = s0;
    *(short8*)&yp[TIX(l, (w<<4) + 8)] = s1;
    __syncthreads();
    // layer1
    short8 bf0 = *(const short8*)&yp[TIX((w<<4) + (l & 15), ((l>>4)<<3))];
    short8 bf1 = *(const short8*)&yp[TIX((w<<4) + (l & 15), 32 + ((l>>4)<<3))];
    f32x4 h[4] = {};
    #pragma unroll
    for (int to = 0; to < 4; ++to){
      h[to] = MFMA16(wf1[to][0], bf0, h[to]);
      h[to] = MFMA16(wf1[to][1], bf1, h[to]);
    }
    int pcol = (w<<4) + (l & 15);
    #pragma unroll
    for (int to = 0; to < 4; ++to)
      #pragma unroll
      for (int r = 0; r < 4; ++r){
        int o = to*16 + ((l>>4)<<2) + r;
        float y = h[to][r] + sh1v[to][r];
        y1p[TIX(pcol, o)] = f2b(y > 0.f ? y : 0.f);
      }
    __syncthreads();
    // layer2 + max
    short8 c0 = *(const short8*)&y1p[TIX(pcol, ((l>>4)<<3))];
    short8 c1 = *(const short8*)&y1p[TIX(pcol, 32 + ((l>>4)<<3))];
    f32x4 h2[4] = {};
    #pragma unroll
    for (int to = 0; to < 4; ++to){
      h2[to] = MFMA16(wf2[to][0], c0, h2[to]);
      h2[to] = MFMA16(wf2[to][1], c1, h2[to]);
    }
    int qloc = ch * 2 + (w >> 1);
    #pragma unroll
    for (int to = 0; to < 4; ++to)
      #pragma unroll
      for (int r = 0; r < 4; ++r){
        float m = h2[to][r] + sh2v[to][r];
        m = m > 0.f ? m : 0.f;               // relu(max) == max(relu)
        #pragma unroll
        for (int s = 1; s <= 8; s <<= 1) m = fmaxf(m, __shfl_xor(m, s));
        if ((l & 15) == 0)
          atomicMax(&omax[qloc*64 + to*16 + ((l>>4)<<2) + r], __float_as_uint(m));
      }
  }
  __syncthreads();
  for (int e = t; e < 1024; e += 256){
    int q = e >> 6, o = e & 63;
    outp[49152 + ((size_t)((b << 6) + o)) * N_ + n0 + q] = __uint_as_float(omax[e]);
  }
}

extern "C" void kernel_launch(void* const* d_in, const int* in_sizes, int n_in,
                              void* d_out, int out_size, void* d_ws, size_t ws_size,
                              hipStream_t stream){
  (void)in_sizes; (void)n_in; (void)out_size; (void)ws_size;
  const float* pos1 = (const float*)d_in[0];
  const float* pos2 = (const float*)d_in[1];
  const float* f1   = (const float*)d_in[2];
  const float* f2   = (const float*)d_in[3];
  const float* W0   = (const float*)d_in[4];
  const float* g0   = (const float*)d_in[5];
  const float* b0   = (const float*)d_in[6];
  const float* W1   = (const float*)d_in[7];
  const float* g1   = (const float*)d_in[8];
  const float* b1   = (const float*)d_in[9];
  const float* W2   = (const float*)d_in[10];
  const float* g2   = (const float*)d_in[11];
  const float* b2   = (const float*)d_in[12];

  char* ws = (char*)d_ws;
  int*   idxb = (int*)ws;                        // 2 MiB: idx[B][N][32]
  float* A    = (float*)(ws + (2u << 20));       // 4 MiB: A[b][j][64]
  float* Cn   = (float*)(ws + (6u << 20));       // 4 MiB: Cn[b][n][64]
  u16*   W1b  = (u16*)  (ws + (10u << 20));      // 8 KiB bf16 [o][c], sc1 folded
  u16*   W2b  = (u16*)  (ws + (10u << 20) + (8u << 10));
  float* st   = (float*)(ws + (10u << 20) + (16u << 10));
  float* sum0   = st;              // 64
  float* sumsq0 = st + 64;         // 64
  float* r0     = st + 128;        // 64
  float* r1     = st + 192;        // 64
  float* G0     = st + 256;        // 4096
  float* G1     = st + 256 + 4096; // 4096
  float* bnp0   = st + 256 + 8192; // 128
  float* bnp1   = bnp0 + 128;
  float* bnp2   = bnp1 + 128;

  hipMemsetAsync(st, 0, (256 + 8192) * sizeof(float), stream);

  k_copy<<<dim3(48), 256, 0, stream>>>((const uint4*)pos1, (uint4*)d_out);
  k_knn<<<dim3(1024, 4), 256, 0, stream>>>(pos1, pos2, idxb);
  k_precomp<0><<<dim3(64, 4), 256, 0, stream>>>(pos2, f2, W0, A);
  k_precomp<1><<<dim3(64, 4), 256, 0, stream>>>(pos1, f1, W0, Cn);
  k_stats0<<<dim3(128, 4), 256, 0, stream>>>(idxb, A, Cn, sum0, sumsq0);
  k_bn0<<<dim3(1), 64, 0, stream>>>(sum0, sumsq0, g0, b0, bnp0);
  k_scaleAC<0><<<dim3(1024), 256, 0, stream>>>(A, bnp0);
  k_scaleAC<1><<<dim3(1024), 256, 0, stream>>>(Cn, bnp0);
  k_gram0<<<dim3(256, 4), 256, 0, stream>>>(idxb, A, Cn, G0, r0);
  k_bnW<<<dim3(1), 64, 0, stream>>>(W1, r0, G0, g1, b1, bnp1, W1b);
  k_gram1<<<dim3(256, 4), 256, 0, stream>>>(idxb, A, Cn, W1b, bnp1, G1, r1);
  k_bnW<<<dim3(1), 64, 0, stream>>>(W2, r1, G1, g2, b2, bnp2, W2b);
  k_final<<<dim3(256, 4), 256, 0, stream>>>(idxb, A, Cn, W1b, W2b, bnp1, bnp2,
                                            (float*)d_out);
}

// Round 5
// 565.114 us; speedup vs baseline: 1.7151x; 1.7151x over previous
//
#include <hip/hip_runtime.h>
#include <hip/hip_bf16.h>

// FlowEmbedding (B=4, N=M=4096, C=64, S=32, mlp=[64,64,64]) — f32 I/O.
// R5: same MFMA structure as R4, but global atomic fan-in removed:
//     G0/G1 -> 128-slot partial slab + reduce kernel; r/sum stats -> slot
//     partials summed in the BN kernels. (R4 post-mortem: 4.19M device-scope
//     atomics to 4096 addrs = 414us stall at the coherence point.)

#define N_ 4096
#define S_ 32
#define PTOT 524288.0f   // B*N*S

typedef unsigned short u16;
typedef unsigned int   u32;
typedef __attribute__((ext_vector_type(8))) short short8;  // 8 bf16 (4 VGPR)
typedef __attribute__((ext_vector_type(4))) float f32x4;

__device__ __forceinline__ u16 f2b(float f){
  __hip_bfloat16 h = __float2bfloat16(f);
  return *(u16*)&h;
}
// swizzled u16 index into a [64][64] bf16 LDS tile (rows 128 B): conflict-free
__device__ __forceinline__ int TIX(int r, int c){ return (r << 6) + (c ^ ((r & 7) << 3)); }
#define MFMA16(a,b,c) __builtin_amdgcn_mfma_f32_16x16x32_bf16((a),(b),(c),0,0,0)

// ---------------- copy pos1 (output 0 passthrough) ---------------------------
__global__ void k_copy(const uint4* __restrict__ s, uint4* __restrict__ d){
  int i = blockIdx.x * 256 + threadIdx.x;   // 48 x 256 = 12288 exact
  d[i] = s[i];
}

// ---------------- KNN: one query per wave, lane-distributed sorted top-32 ----
__global__ __launch_bounds__(256) void k_knn(const float* __restrict__ pos1,
        const float* __restrict__ pos2, int* __restrict__ idxb){
  int b = blockIdx.y;
  int lane = threadIdx.x & 63;
  int n = blockIdx.x * 4 + (threadIdx.x >> 6);
  const float* p1 = pos1 + b * 3 * N_;
  const float* p2 = pos2 + b * 3 * N_;
  float qx = p1[n], qy = p1[N_ + n], qz = p1[2 * N_ + n];
  float v = 3.4e38f; int vi = 0;
  float w32 = 3.4e38f;
  for (int c0 = 0; c0 < N_; c0 += 64){
    int j = c0 + lane;
    float dx = p2[j] - qx;
    float dy = p2[N_ + j] - qy;
    float dz = p2[2 * N_ + j] - qz;
    float dsq = dx * dx + dy * dy + dz * dz;
    unsigned long long mask = __ballot(dsq < w32);
    while (mask){
      int s = __builtin_ctzll(mask); mask &= mask - 1;
      float xd = __shfl(dsq, s);
      int   xj = c0 + s;
      int rank = __popcll(__ballot(v < xd));
      float pv = __shfl_up(v, 1);
      int   pi = __shfl_up(vi, 1);
      if (lane >= rank){
        if (lane == rank){ v = xd; vi = xj; }
        else             { v = pv; vi = pi; }
      }
      if (lane >= 32) v = 3.4e38f;
      w32 = __shfl(v, 31);
    }
  }
  int best = __shfl(vi, 0);
  if (lane < 32){
    int id = (v > 25.0f) ? best : vi;
    idxb[(b * N_ + n) * S_ + lane] = id;
  }
}

// ---------------- layer-0 factorization: A (MODE=0) / Cn (MODE=1) -----------
template<int MODE>
__global__ __launch_bounds__(256) void k_precomp(const float* __restrict__ posx,
        const float* __restrict__ featx, const float* __restrict__ W0,
        float* __restrict__ outp){
  __shared__ float Ws[67][65];
  __shared__ float Xs[67][65];
  int b = blockIdx.y, j0 = blockIdx.x * 64, t = threadIdx.x;
  for (int e = t; e < 67 * 64; e += 256){
    int r = e >> 6, o = e & 63;
    int wc = (MODE == 0) ? r : (r < 3 ? r : r + 64);
    Ws[r][o] = W0[o * 131 + wc];
    float x;
    if (r < 3){ x = posx[(b * 3 + r) * N_ + j0 + o]; if (MODE) x = -x; }
    else        x = featx[(b * 64 + (r - 3)) * N_ + j0 + o];
    Xs[r][o] = x;
  }
  __syncthreads();
  int og = t & 15, sl = t >> 4;
  float acc[4][4] = {};
  for (int r = 0; r < 67; ++r){
    float w0v = Ws[r][og*4+0], w1v = Ws[r][og*4+1], w2v = Ws[r][og*4+2], w3v = Ws[r][og*4+3];
    #pragma unroll
    for (int c = 0; c < 4; ++c){
      float xv = Xs[r][sl*4+c];
      acc[c][0] += xv*w0v; acc[c][1] += xv*w1v; acc[c][2] += xv*w2v; acc[c][3] += xv*w3v;
    }
  }
  #pragma unroll
  for (int c = 0; c < 4; ++c){
    float4 val; val.x = acc[c][0]; val.y = acc[c][1]; val.z = acc[c][2]; val.w = acc[c][3];
    *(float4*)&outp[((size_t)(b * N_ + j0 + sl*4 + c)) * 64 + og*4] = val;
  }
}

// ---------------- stats of h0 (pre-BN0): direct gather, slot partials -------
__global__ __launch_bounds__(256) void k_stats0(const int* __restrict__ idxb,
    const float* __restrict__ A, const float* __restrict__ Cn,
    float* __restrict__ sp1, float* __restrict__ sp2){
  int b = blockIdx.y, n0 = blockIdx.x * 32;
  int c4 = threadIdx.x & 15, sq = threadIdx.x >> 4;
  float4 a1 = {0,0,0,0}, a2 = {0,0,0,0};
  for (int q = 0; q < 32; ++q){
    int n = n0 + q;
    float4 cv = *(const float4*)&Cn[((size_t)(b * N_ + n)) * 64 + c4 * 4];
    const int* ip = idxb + (b * N_ + n) * 32;
    #pragma unroll
    for (int ss = 0; ss < 2; ++ss){
      int j = ip[sq + ss * 16];
      float4 av = *(const float4*)&A[((size_t)(b * N_ + j)) * 64 + c4 * 4];
      float h0 = av.x + cv.x, h1 = av.y + cv.y, h2 = av.z + cv.z, h3 = av.w + cv.w;
      a1.x += h0; a1.y += h1; a1.z += h2; a1.w += h3;
      a2.x += h0*h0; a2.y += h1*h1; a2.z += h2*h2; a2.w += h3*h3;
    }
  }
  __shared__ float red1[16][64];
  __shared__ float red2[16][64];
  *(float4*)&red1[sq][c4*4] = a1;
  *(float4*)&red2[sq][c4*4] = a2;
  __syncthreads();
  int t = threadIdx.x;
  int slot = (blockIdx.x + (blockIdx.y << 7)) & 63;
  if (t < 64){
    float s1 = 0.f, s2 = 0.f;
    #pragma unroll
    for (int k = 0; k < 16; ++k){ s1 += red1[k][t]; s2 += red2[k][t]; }
    atomicAdd(&sp1[slot * 64 + t], s1);
    atomicAdd(&sp2[slot * 64 + t], s2);
  }
}

// ---------------- BN param kernels ------------------------------------------
__global__ void k_bn0(const float* __restrict__ sp1, const float* __restrict__ sp2,
                      const float* g, const float* bb, float* bnp){
  int c = threadIdx.x;
  float s1 = 0.f, s2 = 0.f;
  for (int s = 0; s < 64; ++s){ s1 += sp1[s * 64 + c]; s2 += sp2[s * 64 + c]; }
  float m = s1 * (1.0f / PTOT);
  float v = s2 * (1.0f / PTOT) - m * m;
  v = v > 0.f ? v : 0.f;
  float sc = g[c] * rsqrtf(v + 1e-5f);
  bnp[c] = sc; bnp[64 + c] = bb[c] - m * sc;
}

// stats of h=W*y from Gram; emits bf16 weight copy Wb[o][c] = sc[o]*W[o][c]
__global__ void k_bnW(const float* __restrict__ W, const float* __restrict__ rp,
    const float* __restrict__ G, const float* g, const float* bb, float* bnp,
    u16* __restrict__ Wb){
  __shared__ float r_s[64];
  int o = threadIdx.x;
  float rv = 0.f;
  for (int s = 0; s < 128; ++s) rv += rp[s * 64 + o];
  r_s[o] = rv;
  __syncthreads();
  float mean = 0.f;
  for (int c = 0; c < 64; ++c) mean += W[o * 64 + c] * r_s[c];
  float qq = 0.f;
  for (int c = 0; c < 64; ++c){
    float wc = W[o * 64 + c];
    float t1 = 0.f;
    for (int d = 0; d < 64; ++d) t1 += G[c * 64 + d] * W[o * 64 + d];
    qq += wc * t1;
  }
  float m = mean * (1.0f / PTOT);
  float v = qq * (1.0f / PTOT) - m * m;
  v = v > 0.f ? v : 0.f;
  float sc = g[o] * rsqrtf(v + 1e-5f);
  bnp[o] = sc; bnp[64 + o] = bb[o] - m * sc;
  for (int c = 0; c < 64; ++c) Wb[o * 64 + c] = f2b(sc * W[o * 64 + c]);
}

// ---------------- reduce 128 partial grams -> G; re-zero slab for reuse -----
__global__ void k_reduceG(float* __restrict__ Gp, float* __restrict__ Gout){
  int e = blockIdx.x * 256 + threadIdx.x;    // grid 16 x 256 = 4096
  float v = 0.f;
  for (int s = 0; s < 128; ++s) v += Gp[s * 4096 + e];
  Gout[e] = v;
  for (int s = 0; s < 128; ++s) Gp[s * 4096 + e] = 0.f;
}

// ---------------- fold BN0 into A (MODE=0) / Cn (MODE=1), in place ----------
template<int MODE>
__global__ void k_scaleAC(float* __restrict__ X, const float* __restrict__ bnp){
  int i = blockIdx.x * 256 + threadIdx.x;   // float4 index; 1024 x 256
  float4 v = ((float4*)X)[i];
  int c4 = i & 15;
  float4 sc = *(const float4*)&bnp[c4 * 4];
  if (MODE == 0){
    v.x *= sc.x; v.y *= sc.y; v.z *= sc.z; v.w *= sc.w;
  } else {
    float4 sh = *(const float4*)&bnp[64 + c4 * 4];
    v.x = v.x * sc.x + sh.x; v.y = v.y * sc.y + sh.y;
    v.z = v.z * sc.z + sh.z; v.w = v.w * sc.w + sh.w;
  }
  ((float4*)X)[i] = v;
}

// gather one 64-point chunk, compute y0 = relu(A'+Cn') (f32), return 16 ch vals
#define GATHER_Y0(YARR)                                                       \
  int nq = n0 + ch * 2 + (l >> 5);                                            \
  int jj = idxb[((b << 12) + nq) * 32 + (l & 31)];                            \
  const float* ap = A + (((size_t)((b << 12) + jj)) << 6) + (w << 4);         \
  const float* cp = Cn + (((size_t)((b << 12) + nq)) << 6) + (w << 4);        \
  float YARR[16];                                                             \
  _Pragma("unroll")                                                           \
  for (int k = 0; k < 16; k += 4){                                            \
    float4 av = *(const float4*)(ap + k);                                     \
    float4 cv = *(const float4*)(cp + k);                                     \
    YARR[k+0] = fmaxf(av.x + cv.x, 0.f);                                      \
    YARR[k+1] = fmaxf(av.y + cv.y, 0.f);                                      \
    YARR[k+2] = fmaxf(av.z + cv.z, 0.f);                                      \
    YARR[k+3] = fmaxf(av.w + cv.w, 0.f);                                      \
  }

// ---------------- gram0: G0 partials = sum y0 y0^T (MFMA) -------------------
__global__ __launch_bounds__(256) void k_gram0(const int* __restrict__ idxb,
    const float* __restrict__ A, const float* __restrict__ Cn,
    float* __restrict__ Gp, float* __restrict__ rp0){
  __shared__ u16 yc[4096];                   // y0 [c][p] bf16, swizzled
  int b = blockIdx.y, n0 = blockIdx.x * 16, t = threadIdx.x;
  int l = t & 63, w = t >> 6;
  f32x4 acc[4] = {};
  float rsum[16] = {};
  for (int ch = 0; ch < 8; ++ch){
    GATHER_Y0(yv)                            // lane: p = l, channels w*16..+15
    #pragma unroll
    for (int k = 0; k < 16; ++k){
      rsum[k] += yv[k];
      yc[TIX((w << 4) + k, l)] = f2b(yv[k]);
    }
    __syncthreads();
    #pragma unroll
    for (int ks = 0; ks < 2; ++ks){
      short8 bf = *(const short8*)&yc[TIX((w << 4) + (l & 15), ks * 32 + ((l >> 4) << 3))];
      #pragma unroll
      for (int ta = 0; ta < 4; ++ta){
        short8 af = *(const short8*)&yc[TIX(ta * 16 + (l & 15), ks * 32 + ((l >> 4) << 3))];
        acc[ta] = MFMA16(af, bf, acc[ta]);
      }
    }
    __syncthreads();                         // before next chunk overwrites yc
  }
  int slot = (blockIdx.x + (blockIdx.y << 8)) & 127;
  float* gp = Gp + slot * 4096;
  #pragma unroll
  for (int ta = 0; ta < 4; ++ta)
    #pragma unroll
    for (int r = 0; r < 4; ++r)
      atomicAdd(&gp[(ta*16 + ((l>>4)<<2) + r) * 64 + (w<<4) + (l & 15)], acc[ta][r]);
  #pragma unroll
  for (int i = 0; i < 16; ++i){
    float v = rsum[i];
    #pragma unroll
    for (int s = 32; s >= 1; s >>= 1) v += __shfl_xor(v, s);
    if (l == 0) atomicAdd(&rp0[slot * 64 + (w<<4) + i], v);
  }
}

// ---------------- gram1: y1 = relu(W1b*y0 + sh1); G1 partials (MFMA) --------
__global__ __launch_bounds__(256) void k_gram1(const int* __restrict__ idxb,
    const float* __restrict__ A, const float* __restrict__ Cn,
    const u16* __restrict__ W1b, const float* __restrict__ bnp1,
    float* __restrict__ Gp, float* __restrict__ rp1){
  __shared__ u16 yp[4096];                   // y0 [p][c] bf16, swizzled
  __shared__ u16 y1c[4096];                  // y1 [c][p] bf16, swizzled
  __shared__ float sh1[64];
  __shared__ float rsh[64];
  int b = blockIdx.y, n0 = blockIdx.x * 16, t = threadIdx.x;
  int l = t & 63, w = t >> 6;
  if (t < 64){ sh1[t] = bnp1[64 + t]; rsh[t] = 0.f; }
  short8 wf[4][2];
  #pragma unroll
  for (int to = 0; to < 4; ++to)
    #pragma unroll
    for (int ks = 0; ks < 2; ++ks)
      wf[to][ks] = *(const short8*)&W1b[(to*16 + (l & 15)) * 64 + ks*32 + ((l>>4)<<3)];
  __syncthreads();
  float sh1v[4][4];
  #pragma unroll
  for (int to = 0; to < 4; ++to)
    #pragma unroll
    for (int r = 0; r < 4; ++r)
      sh1v[to][r] = sh1[to*16 + ((l>>4)<<2) + r];
  f32x4 gacc[4] = {};
  float rs[4][4] = {};
  for (int ch = 0; ch < 8; ++ch){
    GATHER_Y0(yv)                            // lane: p = l, channels w*16..+15
    short8 s0, s1;
    #pragma unroll
    for (int i = 0; i < 8; ++i){ s0[i] = (short)f2b(yv[i]); s1[i] = (short)f2b(yv[8+i]); }
    *(short8*)&yp[TIX(l, (w<<4))] = s0;
    *(short8*)&yp[TIX(l, (w<<4) + 8)] = s1;
    __syncthreads();
    // layer1: D[o][p] = sum_c W1b[o][c] * y0[c][p]; wave w owns p-tile w
    short8 bf0 = *(const short8*)&yp[TIX((w<<4) + (l & 15), ((l>>4)<<3))];
    short8 bf1 = *(const short8*)&yp[TIX((w<<4) + (l & 15), 32 + ((l>>4)<<3))];
    f32x4 h[4] = {};
    #pragma unroll
    for (int to = 0; to < 4; ++to){
      h[to] = MFMA16(wf[to][0], bf0, h[to]);
      h[to] = MFMA16(wf[to][1], bf1, h[to]);
    }
    int pcol = (w<<4) + (l & 15);
    #pragma unroll
    for (int to = 0; to < 4; ++to)
      #pragma unroll
      for (int r = 0; r < 4; ++r){
        int o = to*16 + ((l>>4)<<2) + r;
        float y = h[to][r] + sh1v[to][r];
        y = y > 0.f ? y : 0.f;
        rs[to][r] += y;
        y1c[TIX(o, pcol)] = f2b(y);
      }
    __syncthreads();
    // gram over y1
    #pragma unroll
    for (int ks = 0; ks < 2; ++ks){
      short8 bf = *(const short8*)&y1c[TIX((w<<4) + (l & 15), ks*32 + ((l>>4)<<3))];
      #pragma unroll
      for (int ta = 0; ta < 4; ++ta){
        short8 af = *(const short8*)&y1c[TIX(ta*16 + (l & 15), ks*32 + ((l>>4)<<3))];
        gacc[ta] = MFMA16(af, bf, gacc[ta]);
      }
    }
  }
  int slot = (blockIdx.x + (blockIdx.y << 8)) & 127;
  float* gp = Gp + slot * 4096;
  #pragma unroll
  for (int ta = 0; ta < 4; ++ta)
    #pragma unroll
    for (int r = 0; r < 4; ++r)
      atomicAdd(&gp[(ta*16 + ((l>>4)<<2) + r) * 64 + (w<<4) + (l & 15)], gacc[ta][r]);
  #pragma unroll
  for (int to = 0; to < 4; ++to)
    #pragma unroll
    for (int r = 0; r < 4; ++r){
      float v = rs[to][r];
      #pragma unroll
      for (int s = 1; s <= 8; s <<= 1) v += __shfl_xor(v, s);
      if ((l & 15) == 0) atomicAdd(&rsh[to*16 + ((l>>4)<<2) + r], v);
    }
  __syncthreads();
  if (t < 64) atomicAdd(&rp1[slot * 64 + t], rsh[t]);
}

// ---------------- final: layer1 + layer2 + maxpool -> out (MFMA) ------------
__global__ __launch_bounds__(256) void k_final(const int* __restrict__ idxb,
    const float* __restrict__ A, const float* __restrict__ Cn,
    const u16* __restrict__ W1b, const u16* __restrict__ W2b,
    const float* __restrict__ bnp1, const float* __restrict__ bnp2,
    float* __restrict__ outp){
  __shared__ u16 yp[4096];                   // y0 [p][c]
  __shared__ u16 y1p[4096];                  // y1 [p][c]
  __shared__ float sh1[64], sh2[64];
  __shared__ u32 omax[1024];                 // [q][o]
  int b = blockIdx.y, n0 = blockIdx.x * 16, t = threadIdx.x;
  int l = t & 63, w = t >> 6;
  if (t < 64){ sh1[t] = bnp1[64 + t]; sh2[t] = bnp2[64 + t]; }
  for (int e = t; e < 1024; e += 256) omax[e] = 0u;
  short8 wf1[4][2], wf2[4][2];
  #pragma unroll
  for (int to = 0; to < 4; ++to)
    #pragma unroll
    for (int ks = 0; ks < 2; ++ks){
      wf1[to][ks] = *(const short8*)&W1b[(to*16 + (l & 15)) * 64 + ks*32 + ((l>>4)<<3)];
      wf2[to][ks] = *(const short8*)&W2b[(to*16 + (l & 15)) * 64 + ks*32 + ((l>>4)<<3)];
    }
  __syncthreads();
  float sh1v[4][4], sh2v[4][4];
  #pragma unroll
  for (int to = 0; to < 4; ++to)
    #pragma unroll
    for (int r = 0; r < 4; ++r){
      sh1v[to][r] = sh1[to*16 + ((l>>4)<<2) + r];
      sh2v[to][r] = sh2[to*16 + ((l>>4)<<2) + r];
    }
  for (int ch = 0; ch < 8; ++ch){
    GATHER_Y0(yv)
    short8 s0, s1;
    #pragma unroll
    for (int i = 0; i < 8; ++i){ s0[i] = (short)f2b(yv[i]); s1[i] = (short)f2b(yv[8+i]); }
    *(short8*)&yp[TIX(l, (w<<4))] = s0;
    *(short8*)&yp[TIX(l, (w<<4) + 8)] = s1;
    __syncthreads();
    // layer1
    short8 bf0 = *(const short8*)&yp[TIX((w<<4) + (l & 15), ((l>>4)<<3))];
    short8 bf1 = *(const short8*)&yp[TIX((w<<4) + (l & 15), 32 + ((l>>4)<<3))];
    f32x4 h[4] = {};
    #pragma unroll
    for (int to = 0; to < 4; ++to){
      h[to] = MFMA16(wf1[to][0], bf0, h[to]);
      h[to] = MFMA16(wf1[to][1], bf1, h[to]);
    }
    int pcol = (w<<4) + (l & 15);
    #pragma unroll
    for (int to = 0; to < 4; ++to)
      #pragma unroll
      for (int r = 0; r < 4; ++r){
        int o = to*16 + ((l>>4)<<2) + r;
        float y = h[to][r] + sh1v[to][r];
        y1p[TIX(pcol, o)] = f2b(y > 0.f ? y : 0.f);
      }
    __syncthreads();
    // layer2 + max
    short8 c0 = *(const short8*)&y1p[TIX(pcol, ((l>>4)<<3))];
    short8 c1 = *(const short8*)&y1p[TIX(pcol, 32 + ((l>>4)<<3))];
    f32x4 h2[4] = {};
    #pragma unroll
    for (int to = 0; to < 4; ++to){
      h2[to] = MFMA16(wf2[to][0], c0, h2[to]);
      h2[to] = MFMA16(wf2[to][1], c1, h2[to]);
    }
    int qloc = ch * 2 + (w >> 1);
    #pragma unroll
    for (int to = 0; to < 4; ++to)
      #pragma unroll
      for (int r = 0; r < 4; ++r){
        float m = h2[to][r] + sh2v[to][r];
        m = m > 0.f ? m : 0.f;               // relu(max) == max(relu)
        #pragma unroll
        for (int s = 1; s <= 8; s <<= 1) m = fmaxf(m, __shfl_xor(m, s));
        if ((l & 15) == 0)
          atomicMax(&omax[qloc*64 + to*16 + ((l>>4)<<2) + r], __float_as_uint(m));
      }
  }
  __syncthreads();
  for (int e = t; e < 1024; e += 256){
    int q = e >> 6, o = e & 63;
    outp[49152 + ((size_t)((b << 6) + o)) * N_ + n0 + q] = __uint_as_float(omax[e]);
  }
}

extern "C" void kernel_launch(void* const* d_in, const int* in_sizes, int n_in,
                              void* d_out, int out_size, void* d_ws, size_t ws_size,
                              hipStream_t stream){
  (void)in_sizes; (void)n_in; (void)out_size; (void)ws_size;
  const float* pos1 = (const float*)d_in[0];
  const float* pos2 = (const float*)d_in[1];
  const float* f1   = (const float*)d_in[2];
  const float* f2   = (const float*)d_in[3];
  const float* W0   = (const float*)d_in[4];
  const float* g0   = (const float*)d_in[5];
  const float* b0   = (const float*)d_in[6];
  const float* W1   = (const float*)d_in[7];
  const float* g1   = (const float*)d_in[8];
  const float* b1   = (const float*)d_in[9];
  const float* W2   = (const float*)d_in[10];
  const float* g2   = (const float*)d_in[11];
  const float* b2   = (const float*)d_in[12];

  char* ws = (char*)d_ws;
  int*   idxb = (int*)ws;                        // 2 MiB: idx[B][N][32]
  float* A    = (float*)(ws + (2u << 20));       // 4 MiB: A[b][j][64]
  float* Cn   = (float*)(ws + (6u << 20));       // 4 MiB: Cn[b][n][64]
  float* Gp   = (float*)(ws + (10u << 20));      // 2 MiB: 128 x 4096 partials
  float* st2  = (float*)(ws + (12u << 20));
  float* rp0  = st2;               // 128*64 = 8192
  float* rp1  = st2 + 8192;        // 8192
  float* sp1  = st2 + 16384;       // 64*64 = 4096
  float* sp2  = st2 + 20480;       // 4096
  float* G0   = st2 + 24576;       // 4096
  float* G1   = st2 + 28672;       // 4096
  float* bnp0 = st2 + 32768;       // 128
  float* bnp1 = bnp0 + 128;
  float* bnp2 = bnp1 + 128;
  u16*   W1b  = (u16*)(st2 + 33152);  // 4096 bf16
  u16*   W2b  = (u16*)(st2 + 35200);  // 4096 bf16

  // zero Gp + rp0 + rp1 + sp1 + sp2 (contiguous: 2 MiB + 96 KiB)
  hipMemsetAsync(Gp, 0, (2u << 20) + 98304u, stream);

  k_copy<<<dim3(48), 256, 0, stream>>>((const uint4*)pos1, (uint4*)d_out);
  k_knn<<<dim3(1024, 4), 256, 0, stream>>>(pos1, pos2, idxb);
  k_precomp<0><<<dim3(64, 4), 256, 0, stream>>>(pos2, f2, W0, A);
  k_precomp<1><<<dim3(64, 4), 256, 0, stream>>>(pos1, f1, W0, Cn);
  k_stats0<<<dim3(128, 4), 256, 0, stream>>>(idxb, A, Cn, sp1, sp2);
  k_bn0<<<dim3(1), 64, 0, stream>>>(sp1, sp2, g0, b0, bnp0);
  k_scaleAC<0><<<dim3(1024), 256, 0, stream>>>(A, bnp0);
  k_scaleAC<1><<<dim3(1024), 256, 0, stream>>>(Cn, bnp0);
  k_gram0<<<dim3(256, 4), 256, 0, stream>>>(idxb, A, Cn, Gp, rp0);
  k_reduceG<<<dim3(16), 256, 0, stream>>>(Gp, G0);
  k_bnW<<<dim3(1), 64, 0, stream>>>(W1, rp0, G0, g1, b1, bnp1, W1b);
  k_gram1<<<dim3(256, 4), 256, 0, stream>>>(idxb, A, Cn, W1b, bnp1, Gp, rp1);
  k_reduceG<<<dim3(16), 256, 0, stream>>>(Gp, G1);
  k_bnW<<<dim3(1), 64, 0, stream>>>(W2, rp1, G1, g2, b2, bnp2, W2b);
  k_final<<<dim3(256, 4), 256, 0, stream>>>(idxb, A, Cn, W1b, W2b, bnp1, bnp2,
                                            (float*)d_out);
}

// Round 6
// 561.993 us; speedup vs baseline: 1.7246x; 1.0056x over previous
//
#include <hip/hip_runtime.h>
#include <hip/hip_bf16.h>

// FlowEmbedding (B=4, N=M=4096, C=64, S=32, mlp=[64,64,64]) — f32 I/O.
// R6: KNN rewritten as histogram radix-select (no serial insertion sort);
//     BN0 folded into gram/final gathers (k_scaleAC removed). Rest = R5.

#define N_ 4096
#define S_ 32
#define PTOT 524288.0f   // B*N*S

typedef unsigned short u16;
typedef unsigned int   u32;
typedef __attribute__((ext_vector_type(8))) short short8;  // 8 bf16 (4 VGPR)
typedef __attribute__((ext_vector_type(4))) float f32x4;

__device__ __forceinline__ u16 f2b(float f){
  __hip_bfloat16 h = __float2bfloat16(f);
  return *(u16*)&h;
}
// swizzled u16 index into a [64][64] bf16 LDS tile (rows 128 B): conflict-free
__device__ __forceinline__ int TIX(int r, int c){ return (r << 6) + (c ^ ((r & 7) << 3)); }
#define MFMA16(a,b,c) __builtin_amdgcn_mfma_f32_16x16x32_bf16((a),(b),(c),0,0,0)

// ---------------- copy pos1 (output 0 passthrough) ---------------------------
__global__ void k_copy(const uint4* __restrict__ s, uint4* __restrict__ d){
  int i = blockIdx.x * 256 + threadIdx.x;   // 48 x 256 = 12288 exact
  d[i] = s[i];
}

// ---------------- KNN: histogram radix-select, one query per wave ------------
// Pass1: 4096 dists -> regs + exponent hist (x4 replicas). Scan -> bin E.
// Pass2: mantissa-8 hist within E. Scan -> threshold T, K=count(d<T)>=32.
// Collect K to LDS, prune K-32 largest, radius-fix with argmin.
__global__ __launch_bounds__(256) void k_knn(const float* __restrict__ pos1,
        const float* __restrict__ pos2, int* __restrict__ idxb){
  __shared__ u32   hist[4][4][256];   // [wave][replica][bin]
  __shared__ float ldist[4][96];
  __shared__ u32   lidxs[4][96];
  int b = blockIdx.y;
  int l = threadIdx.x & 63;
  int w = threadIdx.x >> 6;
  int n = blockIdx.x * 4 + w;
  const float* p1 = pos1 + b * 3 * N_;
  const float* p2 = pos2 + b * 3 * N_;
  float qx = p1[n], qy = p1[N_ + n], qz = p1[2 * N_ + n];
  for (int e = threadIdx.x; e < 4 * 4 * 256; e += 256) ((u32*)hist)[e] = 0;
  __syncthreads();
  int rep = l & 3;
  float dl[64];
  float minv = 3.4e38f; int mini = 0;
  #pragma unroll
  for (int it = 0; it < 64; ++it){
    int j = it * 64 + l;
    float dx = p2[j] - qx, dy = p2[N_ + j] - qy, dz = p2[2 * N_ + j] - qz;
    float d = fmaf(dx, dx, fmaf(dy, dy, dz * dz));
    dl[it] = d;
    if (d < minv){ minv = d; mini = j; }
    atomicAdd(&hist[w][rep][__float_as_uint(d) >> 23], 1u);
  }
  __syncthreads();
  // ---- scan level 1 (lane covers bins 4l..4l+3, summed over replicas)
  u32 bsum[4]; u32 s = 0;
  #pragma unroll
  for (int k = 0; k < 4; ++k){
    u32 v = hist[w][0][4*l+k] + hist[w][1][4*l+k] + hist[w][2][4*l+k] + hist[w][3][4*l+k];
    bsum[k] = v; s += v;
  }
  u32 c = s;
  #pragma unroll
  for (int d2 = 1; d2 < 64; d2 <<= 1){ u32 t2 = __shfl_up(c, d2); if (l >= d2) c += t2; }
  u32 cb = c - s;
  bool cross = (cb < 32u) && (c >= 32u);
  unsigned long long cm = __ballot(cross);
  int srcLane = __builtin_ctzll(cm);
  int E; u32 C0;
  {
    u32 cc = cb; int e_ = 0; u32 c0 = 0; bool f = false;
    #pragma unroll
    for (int k = 0; k < 4; ++k){
      if (!f && cc + bsum[k] >= 32u){ e_ = 4*l + k; c0 = cc; f = true; }
      cc += bsum[k];
    }
    E = __shfl(e_, srcLane); C0 = __shfl(c0, srcLane);
  }
  // ---- level 2: mantissa bits [22:15] within exponent bin E (replica 0)
  hist[w][0][l] = 0; hist[w][0][64+l] = 0; hist[w][0][128+l] = 0; hist[w][0][192+l] = 0;
  __syncthreads();
  #pragma unroll
  for (int it = 0; it < 64; ++it){
    u32 u = __float_as_uint(dl[it]);
    if ((int)(u >> 23) == E) atomicAdd(&hist[w][0][(u >> 15) & 255], 1u);
  }
  __syncthreads();
  u32 need2 = 32u - C0;
  u32 bsum2[4]; u32 s2 = 0;
  #pragma unroll
  for (int k = 0; k < 4; ++k){ u32 v = hist[w][0][4*l+k]; bsum2[k] = v; s2 += v; }
  u32 c2 = s2;
  #pragma unroll
  for (int d2 = 1; d2 < 64; d2 <<= 1){ u32 t2 = __shfl_up(c2, d2); if (l >= d2) c2 += t2; }
  u32 cb2 = c2 - s2;
  bool cross2 = (cb2 < need2) && (c2 >= need2);
  unsigned long long cm2 = __ballot(cross2);
  int srcLane2 = __builtin_ctzll(cm2);
  int F; u32 K;
  {
    u32 cc = cb2; int f_ = 0; u32 ki = 0; bool fnd = false;
    #pragma unroll
    for (int k = 0; k < 4; ++k){
      if (!fnd && cc + bsum2[k] >= need2){ f_ = 4*l + k; ki = cc + bsum2[k]; fnd = true; }
      cc += bsum2[k];
    }
    F = __shfl(f_, srcLane2); K = C0 + __shfl(ki, srcLane2);
  }
  u32 T = (u32)(((E << 8) + F + 1) << 15);
  // ---- collect candidates with d < T (ballot compaction)
  unsigned long long lmask = (1ull << l) - 1ull;
  u32 base = 0;
  #pragma unroll
  for (int it = 0; it < 64; ++it){
    bool pred = __float_as_uint(dl[it]) < T;
    unsigned long long m = __ballot(pred);
    if (pred){
      int slot = (int)(base + __popcll(m & lmask));
      if (slot < 96){ ldist[w][slot] = dl[it]; lidxs[w][slot] = (u32)(it * 64 + l); }
    }
    base += (u32)__popcll(m);
  }
  int Kc = (int)(K > 96u ? 96u : K);
  // ---- prune Kc-32 largest (expected 0-2 iterations)
  while (Kc > 32){
    float v1 = (l < Kc)      ? ldist[w][l]      : -1.f;
    float v2 = (l + 64 < Kc) ? ldist[w][l + 64] : -1.f;
    int   p  = (v2 > v1) ? (l + 64) : l;
    float v  = fmaxf(v1, v2);
    #pragma unroll
    for (int d2 = 1; d2 < 64; d2 <<= 1){
      float ov = __shfl_xor(v, d2); int op = __shfl_xor(p, d2);
      if (ov > v || (ov == v && op < p)){ v = ov; p = op; }
    }
    if (l == 0){ ldist[w][p] = ldist[w][Kc - 1]; lidxs[w][p] = lidxs[w][Kc - 1]; }
    Kc--;
  }
  // ---- argmin (nearest) for radius replacement
  #pragma unroll
  for (int d2 = 1; d2 < 64; d2 <<= 1){
    float ov = __shfl_xor(minv, d2); int oi = __shfl_xor(mini, d2);
    if (ov < minv || (ov == minv && oi < mini)){ minv = ov; mini = oi; }
  }
  if (l < 32){
    float dd = ldist[w][l];
    int   id = (int)lidxs[w][l];
    if (dd > 25.0f) id = mini;
    idxb[(b * N_ + n) * S_ + l] = id;
  }
}

// ---------------- layer-0 factorization: A (MODE=0) / Cn (MODE=1) -----------
template<int MODE>
__global__ __launch_bounds__(256) void k_precomp(const float* __restrict__ posx,
        const float* __restrict__ featx, const float* __restrict__ W0,
        float* __restrict__ outp){
  __shared__ float Ws[67][65];
  __shared__ float Xs[67][65];
  int b = blockIdx.y, j0 = blockIdx.x * 64, t = threadIdx.x;
  for (int e = t; e < 67 * 64; e += 256){
    int r = e >> 6, o = e & 63;
    int wc = (MODE == 0) ? r : (r < 3 ? r : r + 64);
    Ws[r][o] = W0[o * 131 + wc];
    float x;
    if (r < 3){ x = posx[(b * 3 + r) * N_ + j0 + o]; if (MODE) x = -x; }
    else        x = featx[(b * 64 + (r - 3)) * N_ + j0 + o];
    Xs[r][o] = x;
  }
  __syncthreads();
  int og = t & 15, sl = t >> 4;
  float acc[4][4] = {};
  for (int r = 0; r < 67; ++r){
    float w0v = Ws[r][og*4+0], w1v = Ws[r][og*4+1], w2v = Ws[r][og*4+2], w3v = Ws[r][og*4+3];
    #pragma unroll
    for (int c = 0; c < 4; ++c){
      float xv = Xs[r][sl*4+c];
      acc[c][0] += xv*w0v; acc[c][1] += xv*w1v; acc[c][2] += xv*w2v; acc[c][3] += xv*w3v;
    }
  }
  #pragma unroll
  for (int c = 0; c < 4; ++c){
    float4 val; val.x = acc[c][0]; val.y = acc[c][1]; val.z = acc[c][2]; val.w = acc[c][3];
    *(float4*)&outp[((size_t)(b * N_ + j0 + sl*4 + c)) * 64 + og*4] = val;
  }
}

// ---------------- stats of h0 (pre-BN0): direct gather, slot partials -------
__global__ __launch_bounds__(256) void k_stats0(const int* __restrict__ idxb,
    const float* __restrict__ A, const float* __restrict__ Cn,
    float* __restrict__ sp1, float* __restrict__ sp2){
  int b = blockIdx.y, n0 = blockIdx.x * 32;
  int c4 = threadIdx.x & 15, sq = threadIdx.x >> 4;
  float4 a1 = {0,0,0,0}, a2 = {0,0,0,0};
  for (int q = 0; q < 32; ++q){
    int n = n0 + q;
    float4 cv = *(const float4*)&Cn[((size_t)(b * N_ + n)) * 64 + c4 * 4];
    const int* ip = idxb + (b * N_ + n) * 32;
    #pragma unroll
    for (int ss = 0; ss < 2; ++ss){
      int j = ip[sq + ss * 16];
      float4 av = *(const float4*)&A[((size_t)(b * N_ + j)) * 64 + c4 * 4];
      float h0 = av.x + cv.x, h1 = av.y + cv.y, h2 = av.z + cv.z, h3 = av.w + cv.w;
      a1.x += h0; a1.y += h1; a1.z += h2; a1.w += h3;
      a2.x += h0*h0; a2.y += h1*h1; a2.z += h2*h2; a2.w += h3*h3;
    }
  }
  __shared__ float red1[16][64];
  __shared__ float red2[16][64];
  *(float4*)&red1[sq][c4*4] = a1;
  *(float4*)&red2[sq][c4*4] = a2;
  __syncthreads();
  int t = threadIdx.x;
  int slot = (blockIdx.x + (blockIdx.y << 7)) & 63;
  if (t < 64){
    float s1 = 0.f, s2 = 0.f;
    #pragma unroll
    for (int k = 0; k < 16; ++k){ s1 += red1[k][t]; s2 += red2[k][t]; }
    atomicAdd(&sp1[slot * 64 + t], s1);
    atomicAdd(&sp2[slot * 64 + t], s2);
  }
}

// ---------------- BN param kernels ------------------------------------------
__global__ void k_bn0(const float* __restrict__ sp1, const float* __restrict__ sp2,
                      const float* g, const float* bb, float* bnp){
  int c = threadIdx.x;
  float s1 = 0.f, s2 = 0.f;
  for (int s = 0; s < 64; ++s){ s1 += sp1[s * 64 + c]; s2 += sp2[s * 64 + c]; }
  float m = s1 * (1.0f / PTOT);
  float v = s2 * (1.0f / PTOT) - m * m;
  v = v > 0.f ? v : 0.f;
  float sc = g[c] * rsqrtf(v + 1e-5f);
  bnp[c] = sc; bnp[64 + c] = bb[c] - m * sc;
}

// stats of h=W*y from Gram; emits bf16 weight copy Wb[o][c] = sc[o]*W[o][c]
__global__ void k_bnW(const float* __restrict__ W, const float* __restrict__ rp,
    const float* __restrict__ G, const float* g, const float* bb, float* bnp,
    u16* __restrict__ Wb){
  __shared__ float r_s[64];
  int o = threadIdx.x;
  float rv = 0.f;
  for (int s = 0; s < 128; ++s) rv += rp[s * 64 + o];
  r_s[o] = rv;
  __syncthreads();
  float mean = 0.f;
  for (int c = 0; c < 64; ++c) mean += W[o * 64 + c] * r_s[c];
  float qq = 0.f;
  for (int c = 0; c < 64; ++c){
    float wc = W[o * 64 + c];
    float t1 = 0.f;
    for (int d = 0; d < 64; ++d) t1 += G[c * 64 + d] * W[o * 64 + d];
    qq += wc * t1;
  }
  float m = mean * (1.0f / PTOT);
  float v = qq * (1.0f / PTOT) - m * m;
  v = v > 0.f ? v : 0.f;
  float sc = g[o] * rsqrtf(v + 1e-5f);
  bnp[o] = sc; bnp[64 + o] = bb[o] - m * sc;
  for (int c = 0; c < 64; ++c) Wb[o * 64 + c] = f2b(sc * W[o * 64 + c]);
}

// ---------------- reduce 128 partial grams -> G; re-zero slab for reuse -----
__global__ void k_reduceG(float* __restrict__ Gp, float* __restrict__ Gout){
  int e = blockIdx.x * 256 + threadIdx.x;    // grid 16 x 256 = 4096
  float v = 0.f;
  for (int s = 0; s < 128; ++s) v += Gp[s * 4096 + e];
  Gout[e] = v;
  for (int s = 0; s < 128; ++s) Gp[s * 4096 + e] = 0.f;
}

// gather one 64-point chunk: y0 = relu(fma(sc0, A+Cn, sh0)) — BN0 on the fly
#define GATHER_Y0(YARR)                                                       \
  int nq = n0 + ch * 2 + (l >> 5);                                            \
  int jj = idxb[((b << 12) + nq) * 32 + (l & 31)];                            \
  const float* ap = A + (((size_t)((b << 12) + jj)) << 6) + (w << 4);         \
  const float* cp = Cn + (((size_t)((b << 12) + nq)) << 6) + (w << 4);        \
  float YARR[16];                                                             \
  _Pragma("unroll")                                                           \
  for (int kk = 0; kk < 16; kk += 4){                                         \
    float4 av = *(const float4*)(ap + kk);                                    \
    float4 cv = *(const float4*)(cp + kk);                                    \
    int q4 = kk >> 2;                                                         \
    YARR[kk+0] = fmaxf(fmaf(scv[q4].x, av.x + cv.x, shv[q4].x), 0.f);         \
    YARR[kk+1] = fmaxf(fmaf(scv[q4].y, av.y + cv.y, shv[q4].y), 0.f);         \
    YARR[kk+2] = fmaxf(fmaf(scv[q4].z, av.z + cv.z, shv[q4].z), 0.f);         \
    YARR[kk+3] = fmaxf(fmaf(scv[q4].w, av.w + cv.w, shv[q4].w), 0.f);         \
  }

#define LOAD_BN0                                                              \
  float4 scv[4], shv[4];                                                      \
  _Pragma("unroll")                                                           \
  for (int k = 0; k < 4; ++k){                                                \
    scv[k] = *((const float4*)bnp0 + (w << 2) + k);                           \
    shv[k] = *((const float4*)bnp0 + 16 + (w << 2) + k);                      \
  }

// ---------------- gram0: G0 partials = sum y0 y0^T (MFMA) -------------------
__global__ __launch_bounds__(256) void k_gram0(const int* __restrict__ idxb,
    const float* __restrict__ A, const float* __restrict__ Cn,
    const float* __restrict__ bnp0, float* __restrict__ Gp, float* __restrict__ rp0){
  __shared__ u16 yc[4096];                   // y0 [c][p] bf16, swizzled
  int b = blockIdx.y, n0 = blockIdx.x * 16, t = threadIdx.x;
  int l = t & 63, w = t >> 6;
  LOAD_BN0
  f32x4 acc[4] = {};
  float rsum[16] = {};
  for (int ch = 0; ch < 8; ++ch){
    GATHER_Y0(yv)                            // lane: p = l, channels w*16..+15
    #pragma unroll
    for (int k = 0; k < 16; ++k){
      rsum[k] += yv[k];
      yc[TIX((w << 4) + k, l)] = f2b(yv[k]);
    }
    __syncthreads();
    #pragma unroll
    for (int ks = 0; ks < 2; ++ks){
      short8 bf = *(const short8*)&yc[TIX((w << 4) + (l & 15), ks * 32 + ((l >> 4) << 3))];
      #pragma unroll
      for (int ta = 0; ta < 4; ++ta){
        short8 af = *(const short8*)&yc[TIX(ta * 16 + (l & 15), ks * 32 + ((l >> 4) << 3))];
        acc[ta] = MFMA16(af, bf, acc[ta]);
      }
    }
    __syncthreads();                         // before next chunk overwrites yc
  }
  int slot = (blockIdx.x + (blockIdx.y << 8)) & 127;
  float* gp = Gp + slot * 4096;
  #pragma unroll
  for (int ta = 0; ta < 4; ++ta)
    #pragma unroll
    for (int r = 0; r < 4; ++r)
      atomicAdd(&gp[(ta*16 + ((l>>4)<<2) + r) * 64 + (w<<4) + (l & 15)], acc[ta][r]);
  #pragma unroll
  for (int i = 0; i < 16; ++i){
    float v = rsum[i];
    #pragma unroll
    for (int s = 32; s >= 1; s >>= 1) v += __shfl_xor(v, s);
    if (l == 0) atomicAdd(&rp0[slot * 64 + (w<<4) + i], v);
  }
}

// ---------------- gram1: y1 = relu(W1b*y0 + sh1); G1 partials (MFMA) --------
__global__ __launch_bounds__(256) void k_gram1(const int* __restrict__ idxb,
    const float* __restrict__ A, const float* __restrict__ Cn,
    const float* __restrict__ bnp0, const u16* __restrict__ W1b,
    const float* __restrict__ bnp1, float* __restrict__ Gp, float* __restrict__ rp1){
  __shared__ u16 yp[4096];                   // y0 [p][c] bf16, swizzled
  __shared__ u16 y1c[4096];                  // y1 [c][p] bf16, swizzled
  __shared__ float sh1[64];
  __shared__ float rsh[64];
  int b = blockIdx.y, n0 = blockIdx.x * 16, t = threadIdx.x;
  int l = t & 63, w = t >> 6;
  LOAD_BN0
  if (t < 64){ sh1[t] = bnp1[64 + t]; rsh[t] = 0.f; }
  short8 wf[4][2];
  #pragma unroll
  for (int to = 0; to < 4; ++to)
    #pragma unroll
    for (int ks = 0; ks < 2; ++ks)
      wf[to][ks] = *(const short8*)&W1b[(to*16 + (l & 15)) * 64 + ks*32 + ((l>>4)<<3)];
  __syncthreads();
  float sh1v[4][4];
  #pragma unroll
  for (int to = 0; to < 4; ++to)
    #pragma unroll
    for (int r = 0; r < 4; ++r)
      sh1v[to][r] = sh1[to*16 + ((l>>4)<<2) + r];
  f32x4 gacc[4] = {};
  float rs[4][4] = {};
  for (int ch = 0; ch < 8; ++ch){
    GATHER_Y0(yv)                            // lane: p = l, channels w*16..+15
    short8 s0, s1;
    #pragma unroll
    for (int i = 0; i < 8; ++i){ s0[i] = (short)f2b(yv[i]); s1[i] = (short)f2b(yv[8+i]); }
    *(short8*)&yp[TIX(l, (w<<4))] = s0;
    *(short8*)&yp[TIX(l, (w<<4) + 8)] = s1;
    __syncthreads();
    // layer1: D[o][p] = sum_c W1b[o][c] * y0[c][p]; wave w owns p-tile w
    short8 bf0 = *(const short8*)&yp[TIX((w<<4) + (l & 15), ((l>>4)<<3))];
    short8 bf1 = *(const short8*)&yp[TIX((w<<4) + (l & 15), 32 + ((l>>4)<<3))];
    f32x4 h[4] = {};
    #pragma unroll
    for (int to = 0; to < 4; ++to){
      h[to] = MFMA16(wf[to][0], bf0, h[to]);
      h[to] = MFMA16(wf[to][1], bf1, h[to]);
    }
    int pcol = (w<<4) + (l & 15);
    #pragma unroll
    for (int to = 0; to < 4; ++to)
      #pragma unroll
      for (int r = 0; r < 4; ++r){
        int o = to*16 + ((l>>4)<<2) + r;
        float y = h[to][r] + sh1v[to][r];
        y = y > 0.f ? y : 0.f;
        rs[to][r] += y;
        y1c[TIX(o, pcol)] = f2b(y);
      }
    __syncthreads();
    // gram over y1
    #pragma unroll
    for (int ks = 0; ks < 2; ++ks){
      short8 bf = *(const short8*)&y1c[TIX((w<<4) + (l & 15), ks*32 + ((l>>4)<<3))];
      #pragma unroll
      for (int ta = 0; ta < 4; ++ta){
        short8 af = *(const short8*)&y1c[TIX(ta*16 + (l & 15), ks*32 + ((l>>4)<<3))];
        gacc[ta] = MFMA16(af, bf, gacc[ta]);
      }
    }
  }
  int slot = (blockIdx.x + (blockIdx.y << 8)) & 127;
  float* gp = Gp + slot * 4096;
  #pragma unroll
  for (int ta = 0; ta < 4; ++ta)
    #pragma unroll
    for (int r = 0; r < 4; ++r)
      atomicAdd(&gp[(ta*16 + ((l>>4)<<2) + r) * 64 + (w<<4) + (l & 15)], gacc[ta][r]);
  #pragma unroll
  for (int to = 0; to < 4; ++to)
    #pragma unroll
    for (int r = 0; r < 4; ++r){
      float v = rs[to][r];
      #pragma unroll
      for (int s = 1; s <= 8; s <<= 1) v += __shfl_xor(v, s);
      if ((l & 15) == 0) atomicAdd(&rsh[to*16 + ((l>>4)<<2) + r], v);
    }
  __syncthreads();
  if (t < 64) atomicAdd(&rp1[slot * 64 + t], rsh[t]);
}

// ---------------- final: layer1 + layer2 + maxpool -> out (MFMA) ------------
__global__ __launch_bounds__(256) void k_final(const int* __restrict__ idxb,
    const float* __restrict__ A, const float* __restrict__ Cn,
    const float* __restrict__ bnp0, const u16* __restrict__ W1b,
    const u16* __restrict__ W2b, const float* __restrict__ bnp1,
    const float* __restrict__ bnp2, float* __restrict__ outp){
  __shared__ u16 yp[4096];                   // y0 [p][c]
  __shared__ u16 y1p[4096];                  // y1 [p][c]
  __shared__ float sh1[64], sh2[64];
  __shared__ u32 omax[1024];                 // [q][o]
  int b = blockIdx.y, n0 = blockIdx.x * 16, t = threadIdx.x;
  int l = t & 63, w = t >> 6;
  LOAD_BN0
  if (t < 64){ sh1[t] = bnp1[64 + t]; sh2[t] = bnp2[64 + t]; }
  for (int e = t; e < 1024; e += 256) omax[e] = 0u;
  short8 wf1[4][2], wf2[4][2];
  #pragma unroll
  for (int to = 0; to < 4; ++to)
    #pragma unroll
    for (int ks = 0; ks < 2; ++ks){
      wf1[to][ks] = *(const short8*)&W1b[(to*16 + (l & 15)) * 64 + ks*32 + ((l>>4)<<3)];
      wf2[to][ks] = *(const short8*)&W2b[(to*16 + (l & 15)) * 64 + ks*32 + ((l>>4)<<3)];
    }
  __syncthreads();
  float sh1v[4][4], sh2v[4][4];
  #pragma unroll
  for (int to = 0; to < 4; ++to)
    #pragma unroll
    for (int r = 0; r < 4; ++r){
      sh1v[to][r] = sh1[to*16 + ((l>>4)<<2) + r];
      sh2v[to][r] = sh2[to*16 + ((l>>4)<<2) + r];
    }
  for (int ch = 0; ch < 8; ++ch){
    GATHER_Y0(yv)
    short8 s0, s1;
    #pragma unroll
    for (int i = 0; i < 8; ++i){ s0[i] = (short)f2b(yv[i]); s1[i] = (short)f2b(yv[8+i]); }
    *(short8*)&yp[TIX(l, (w<<4))] = s0;
    *(short8*)&yp[TIX(l, (w<<4) + 8)] = s1;
    __syncthreads();
    // layer1
    short8 bf0 = *(const short8*)&yp[TIX((w<<4) + (l & 15), ((l>>4)<<3))];
    short8 bf1 = *(const short8*)&yp[TIX((w<<4) + (l & 15), 32 + ((l>>4)<<3))];
    f32x4 h[4] = {};
    #pragma unroll
    for (int to = 0; to < 4; ++to){
      h[to] = MFMA16(wf1[to][0], bf0, h[to]);
      h[to] = MFMA16(wf1[to][1], bf1, h[to]);
    }
    int pcol = (w<<4) + (l & 15);
    #pragma unroll
    for (int to = 0; to < 4; ++to)
      #pragma unroll
      for (int r = 0; r < 4; ++r){
        int o = to*16 + ((l>>4)<<2) + r;
        float y = h[to][r] + sh1v[to][r];
        y1p[TIX(pcol, o)] = f2b(y > 0.f ? y : 0.f);
      }
    __syncthreads();
    // layer2 + max
    short8 c0 = *(const short8*)&y1p[TIX(pcol, ((l>>4)<<3))];
    short8 c1 = *(const short8*)&y1p[TIX(pcol, 32 + ((l>>4)<<3))];
    f32x4 h2[4] = {};
    #pragma unroll
    for (int to = 0; to < 4; ++to){
      h2[to] = MFMA16(wf2[to][0], c0, h2[to]);
      h2[to] = MFMA16(wf2[to][1], c1, h2[to]);
    }
    int qloc = ch * 2 + (w >> 1);
    #pragma unroll
    for (int to = 0; to < 4; ++to)
      #pragma unroll
      for (int r = 0; r < 4; ++r){
        float m = h2[to][r] + sh2v[to][r];
        m = m > 0.f ? m : 0.f;               // relu(max) == max(relu)
        #pragma unroll
        for (int s = 1; s <= 8; s <<= 1) m = fmaxf(m, __shfl_xor(m, s));
        if ((l & 15) == 0)
          atomicMax(&omax[qloc*64 + to*16 + ((l>>4)<<2) + r], __float_as_uint(m));
      }
  }
  __syncthreads();
  for (int e = t; e < 1024; e += 256){
    int q = e >> 6, o = e & 63;
    outp[49152 + ((size_t)((b << 6) + o)) * N_ + n0 + q] = __uint_as_float(omax[e]);
  }
}

extern "C" void kernel_launch(void* const* d_in, const int* in_sizes, int n_in,
                              void* d_out, int out_size, void* d_ws, size_t ws_size,
                              hipStream_t stream){
  (void)in_sizes; (void)n_in; (void)out_size; (void)ws_size;
  const float* pos1 = (const float*)d_in[0];
  const float* pos2 = (const float*)d_in[1];
  const float* f1   = (const float*)d_in[2];
  const float* f2   = (const float*)d_in[3];
  const float* W0   = (const float*)d_in[4];
  const float* g0   = (const float*)d_in[5];
  const float* b0   = (const float*)d_in[6];
  const float* W1   = (const float*)d_in[7];
  const float* g1   = (const float*)d_in[8];
  const float* b1   = (const float*)d_in[9];
  const float* W2   = (const float*)d_in[10];
  const float* g2   = (const float*)d_in[11];
  const float* b2   = (const float*)d_in[12];

  char* ws = (char*)d_ws;
  int*   idxb = (int*)ws;                        // 2 MiB: idx[B][N][32]
  float* A    = (float*)(ws + (2u << 20));       // 4 MiB: A[b][j][64]
  float* Cn   = (float*)(ws + (6u << 20));       // 4 MiB: Cn[b][n][64]
  float* Gp   = (float*)(ws + (10u << 20));      // 2 MiB: 128 x 4096 partials
  float* st2  = (float*)(ws + (12u << 20));
  float* rp0  = st2;               // 128*64 = 8192
  float* rp1  = st2 + 8192;        // 8192
  float* sp1  = st2 + 16384;       // 64*64 = 4096
  float* sp2  = st2 + 20480;       // 4096
  float* G0   = st2 + 24576;       // 4096
  float* G1   = st2 + 28672;       // 4096
  float* bnp0 = st2 + 32768;       // 128
  float* bnp1 = bnp0 + 128;
  float* bnp2 = bnp1 + 128;
  u16*   W1b  = (u16*)(st2 + 33152);  // 4096 bf16
  u16*   W2b  = (u16*)(st2 + 35200);  // 4096 bf16

  // zero Gp + rp0 + rp1 + sp1 + sp2 (contiguous: 2 MiB + 96 KiB)
  hipMemsetAsync(Gp, 0, (2u << 20) + 98304u, stream);

  k_copy<<<dim3(48), 256, 0, stream>>>((const uint4*)pos1, (uint4*)d_out);
  k_knn<<<dim3(1024, 4), 256, 0, stream>>>(pos1, pos2, idxb);
  k_precomp<0><<<dim3(64, 4), 256, 0, stream>>>(pos2, f2, W0, A);
  k_precomp<1><<<dim3(64, 4), 256, 0, stream>>>(pos1, f1, W0, Cn);
  k_stats0<<<dim3(128, 4), 256, 0, stream>>>(idxb, A, Cn, sp1, sp2);
  k_bn0<<<dim3(1), 64, 0, stream>>>(sp1, sp2, g0, b0, bnp0);
  k_gram0<<<dim3(256, 4), 256, 0, stream>>>(idxb, A, Cn, bnp0, Gp, rp0);
  k_reduceG<<<dim3(16), 256, 0, stream>>>(Gp, G0);
  k_bnW<<<dim3(1), 64, 0, stream>>>(W1, rp0, G0, g1, b1, bnp1, W1b);
  k_gram1<<<dim3(256, 4), 256, 0, stream>>>(idxb, A, Cn, bnp0, W1b, bnp1, Gp, rp1);
  k_reduceG<<<dim3(16), 256, 0, stream>>>(Gp, G1);
  k_bnW<<<dim3(1), 64, 0, stream>>>(W2, rp1, G1, g2, b2, bnp2, W2b);
  k_final<<<dim3(256, 4), 256, 0, stream>>>(idxb, A, Cn, bnp0, W1b, W2b, bnp1, bnp2,
                                            (float*)d_out);
}